// Round 4
// baseline (750.775 us; speedup 1.0000x reference)
//
#include <hip/hip_runtime.h>
#include <hip/hip_bf16.h>

// AlignmentContrastiveLoss on MI355X.
// Pipeline:
//   K1 normalize_pack: fp32 L2-normalize rows of im_set/s_seq, drop CLS/special
//      tokens, cast to bf16. Both packed DENSE: im' [256][36][1024],
//      s' [256][30][1024].
//   K2 gemm_scores: bf16 MFMA GEMM per block: M=144 (4 images x 36),
//      N=240 (8 sentences x 30), K=1024. 4 waves (256 thr), each wave owns
//      4 N-tiles x all 9 M-tiles. DOUBLE-BUFFERED K-pipeline with BK=32:
//      STAGE(next) issued before compute(cur), one barrier/iter -> the
//      vmcnt(0) drain at the barrier is cheap (loads had a full compute
//      phase in flight). LDS 2 x 24 KB -> 3 blocks/CU.
//      Staging: global_load_lds_dwordx4 DMA into LINEAR 64B rows, XOR chunk
//      swizzle phys = logical ^ (row&3) via inverse-swizzled global source +
//      swizzled ds_read (both-sides rule).
//   K3 loss_partial + loss_final: contrastive loss, 64-block parallel.

typedef __attribute__((ext_vector_type(8))) short bf16x8;
typedef __attribute__((ext_vector_type(4))) float f32x4;

#define NB   256
#define DIM  1024
#define LI   36     // valid image regions (dense pack stride)
#define LS   30     // valid words (dense pack stride)
#define MT   9      // M-tiles per block (144 rows)
#define NT   15     // N-tiles per block (240 rows)
#define BUFB 24576  // bytes per LDS buffer: A 9 KB + B 15 KB
#define BOFF 9216   // B region byte offset within a buffer

static __device__ inline ushort f2bf(float x) {
    union { __hip_bfloat16 h; ushort u; } cvt;
    cvt.h = __float2bfloat16(x);
    return cvt.u;
}

static __device__ __forceinline__ void gload_lds16(const void* g, void* l) {
    __builtin_amdgcn_global_load_lds(
        (const __attribute__((address_space(1))) void*)g,
        (__attribute__((address_space(3))) void*)l, 16, 0, 0);
}

// One wave per output row; every row is a real (valid) row.
__global__ __launch_bounds__(256) void normalize_pack(
    const float* __restrict__ im, const float* __restrict__ sq,
    short* __restrict__ imp, short* __restrict__ sp)
{
    const int gw   = (blockIdx.x * 256 + threadIdx.x) >> 6;
    const int lane = threadIdx.x & 63;
    const int NIM  = NB * LI;   // 9216 dense image rows

    const float* src;
    short* dst;
    if (gw < NIM) {
        int b = gw / LI, i = gw - b * LI;
        dst = imp + (size_t)gw * DIM;
        src = im + ((size_t)b * 37 + i + 1) * DIM;   // drop CLS region 0
    } else {
        int g2 = gw - NIM;
        int b = g2 / LS, j = g2 - b * LS;
        dst = sp + (size_t)g2 * DIM;
        src = sq + ((size_t)b * 33 + j + 1) * DIM;   // rows 1..30 of 33
    }

    const float4* s4 = (const float4*)src;
    float4 v[4];
    float ss = 0.f;
    #pragma unroll
    for (int t = 0; t < 4; ++t) {
        float4 x = s4[lane + 64 * t];
        v[t] = x;
        ss += x.x * x.x + x.y * x.y + x.z * x.z + x.w * x.w;
    }
    #pragma unroll
    for (int o = 32; o >= 1; o >>= 1) ss += __shfl_xor(ss, o, 64);
    float scale = 1.0f / fmaxf(sqrtf(ss), 1e-12f);
    ushort4* d4 = (ushort4*)dst;
    #pragma unroll
    for (int t = 0; t < 4; ++t) {
        float4 x = v[t];
        ushort4 o;
        o.x = f2bf(x.x * scale);
        o.y = f2bf(x.y * scale);
        o.z = f2bf(x.z * scale);
        o.w = f2bf(x.w * scale);
        d4[lane + 64 * t] = o;
    }
}

// Block: 256 threads = 4 waves. blockIdx.x -> 4 images (144 dense rows),
// blockIdx.y -> 8 sentences (240 dense rows). Wave w owns N-tiles 4w..4w+3
// (wave 3: tiles 12..14 only), all 9 M-tiles.
//
// LDS per buffer: A rows 0..143 at byte row*64, B rows 0..239 at BOFF+row*64.
// Rows are 32 bf16 = 64 B = 4 chunks of 16 B, XOR-swizzled:
//   physical_chunk = logical_chunk ^ (row & 3)
// One DMA instr stages 16 rows (1 KB): lane i -> row r0+(i>>2), phys chunk
// (i&3); global source logical chunk = (i&3)^((i>>2)&3)  [r0 % 4 == 0].
// Read side: tile row bases are multiples of 16 -> row&3 = l15&3 -> phys
// chunk = q ^ (l15&3), a per-lane constant. Bank load is exactly 8 dwords
// per bank per wave access -> conflict-free minimum.
__global__ __launch_bounds__(256, 3) void gemm_scores(
    const short* __restrict__ imp, const short* __restrict__ sp,
    const int* __restrict__ im_len, const int* __restrict__ s_len,
    float* __restrict__ scores)
{
    __shared__ __align__(1024) char lds[2 * BUFB];   // 48 KB double buffer
    __shared__ float sred[4][4][3];                  // [wave][img][sent-slot]

    const int tid  = threadIdx.x;
    const int wave = tid >> 6;
    const int lane = tid & 63;
    const int q    = lane >> 4;
    const int l15  = lane & 15;
    const int b0   = blockIdx.x * 4;
    const int c0   = blockIdx.y * 8;

    f32x4 acc[MT][4];
    #pragma unroll
    for (int mt = 0; mt < MT; ++mt)
        #pragma unroll
        for (int t = 0; t < 4; ++t)
            acc[mt][t] = (f32x4){0.f, 0.f, 0.f, 0.f};

    // Staging: 24 chunks of 1 KB per K-slice (A: 0..8, B: 9..23), 6 per wave.
    const int r_in = lane >> 2;                 // row within the 16-row chunk
    const int sch  = (lane & 3) ^ (r_in & 3);   // inverse-swizzled chunk
    const char* gsrc[6];
    int ldsoff[6];
    #pragma unroll
    for (int it = 0; it < 6; ++it) {
        const int cid = wave * 6 + it;
        ldsoff[it] = cid * 1024;
        if (cid < 9)
            gsrc[it] = (const char*)imp
                + ((size_t)(b0 * LI) + cid * 16 + r_in) * (DIM * 2) + sch * 16;
        else
            gsrc[it] = (const char*)sp
                + ((size_t)(c0 * LS) + (cid - 9) * 16 + r_in) * (DIM * 2) + sch * 16;
    }

    // Read-side swizzled chunk byte offset (per-lane constant).
    const int cs = (q ^ (l15 & 3)) * 16;

    // prologue: stage K-slice 0 into buffer 0
    #pragma unroll
    for (int it = 0; it < 6; ++it)
        gload_lds16(gsrc[it], lds + ldsoff[it]);
    __syncthreads();   // vmcnt(0) drain

    auto kstep = [&](int curoff, int nxtoff, int kbn, bool do_stage) {
        if (do_stage) {
            #pragma unroll
            for (int it = 0; it < 6; ++it)
                gload_lds16(gsrc[it] + kbn, lds + nxtoff + ldsoff[it]);
        }
        bf16x8 bfr[4];
        #pragma unroll
        for (int t = 0; t < 4; ++t) {
            const int nt = wave * 4 + t;
            if (nt < NT)   // wave-uniform; speculated read stays in-bounds
                bfr[t] = *(const bf16x8*)(lds + curoff + BOFF + (nt * 16 + l15) * 64 + cs);
        }
        #pragma unroll
        for (int mt = 0; mt < MT; ++mt) {
            bf16x8 af = *(const bf16x8*)(lds + curoff + (mt * 16 + l15) * 64 + cs);
            #pragma unroll
            for (int t = 0; t < 4; ++t)
                if (wave * 4 + t < NT)
                    acc[mt][t] = __builtin_amdgcn_mfma_f32_16x16x32_bf16(
                        af, bfr[t], acc[mt][t], 0, 0, 0);
        }
        __syncthreads();   // drains this iter's stage (in flight all compute)
    };

    // 32 K-slices of 32: compute cur while staging next (one barrier/iter).
    for (int kk = 0; kk < 16; ++kk) {
        kstep(0, BUFB, (2 * kk + 1) * 64, true);
        kstep(BUFB, 0, (2 * kk + 2) * 64, kk < 15);
    }

    // ---- Fused epilogue ----
    // C/D layout: lane holds col = l15, row = q*4 + r.
    // Packed A row g = mt*16 + q*4 + r; image = (4*mt+q)/9, region = g - 36*image.
    // Packed B col = nt*16 + l15; sentence sidx = col/30, word j = col - 30*sidx.
    int il[4];
    #pragma unroll
    for (int bb = 0; bb < 4; ++bb) il[bb] = im_len[b0 + bb] - 1;   // in [9, 36]

    // Wave w covers cols [64w, 64w+64) -> up to 3 sentences, base (64w)/30.
    const int sbase = (64 * wave) / 30;
    float part[4][3] = {{0.f,0.f,0.f},{0.f,0.f,0.f},{0.f,0.f,0.f},{0.f,0.f,0.f}};

    #pragma unroll
    for (int t = 0; t < 4; ++t) {
        const int nt = wave * 4 + t;
        if (nt >= NT) continue;                     // wave-uniform
        const int col  = nt * 16 + l15;             // 0..239
        const int sidx = col / 30;                  // per-lane sentence
        const int j    = col - 30 * sidx;           // word index
        const int sl   = s_len[c0 + sidx] - 3;      // valid words, in [5, 30]
        const bool jv  = (j < sl);
        const int s_begin = (nt * 16) / 30;         // wave-uniform
        const int s_end   = (nt * 16 + 15) / 30;

        #pragma unroll
        for (int bb = 0; bb < 4; ++bb) {
            const int ilb = il[bb];
            float m = -3.4e38f;
            #pragma unroll
            for (int mt = 0; mt < MT; ++mt) {
                const int im_lo = (4 * mt) / 9;          // compile-time
                const int im_hi = (4 * mt + 3) / 9;      // compile-time
                const int thr   = 9 * im_hi - 4 * mt;    // q >= thr -> im_hi
                #pragma unroll
                for (int r = 0; r < 4; ++r) {
                    const float v = acc[mt][t][r];
                    const int base = mt * 16 + q * 4 + r;
                    if (im_lo == im_hi) {
                        if (im_lo == bb) {
                            const int i = base - 36 * bb;
                            if (i < ilb) m = fmaxf(m, v);
                        }
                    } else {
                        const bool hi = (q >= thr);
                        if (!hi && im_lo == bb) {
                            const int i = base - 36 * bb;
                            if (i < ilb) m = fmaxf(m, v);
                        } else if (hi && im_hi == bb) {
                            const int i = base - 36 * bb;
                            if (i < ilb) m = fmaxf(m, v);
                        }
                    }
                }
            }
            // combine the 4 row-quads -> full max over image bb's regions
            m = fmaxf(m, __shfl_xor(m, 16, 64));
            m = fmaxf(m, __shfl_xor(m, 32, 64));
            // masked (zeroed) rows participate in the max only when il < 36
            if (ilb < LI) m = fmaxf(m, 0.f);
            const float c = (q == 0 && jv) ? m : 0.f;   // count each col once
            #pragma unroll
            for (int slot = 0; slot < 3; ++slot) {
                const int s = sbase + slot;
                if (s >= s_begin && s <= s_end) {        // wave-uniform
                    float v = (sidx == s) ? c : 0.f;
                    #pragma unroll
                    for (int off = 32; off >= 1; off >>= 1) v += __shfl_xor(v, off, 64);
                    part[bb][slot] += v;
                }
            }
        }
    }

    if (lane == 0) {
        #pragma unroll
        for (int bb = 0; bb < 4; ++bb)
            #pragma unroll
            for (int slot = 0; slot < 3; ++slot)
                sred[wave][bb][slot] = part[bb][slot];
    }
    __syncthreads();
    // 32 score cells: tid -> (bb = tid>>3, s = tid&7); sentence s gathers from
    // the waves whose 64-col window overlaps cols [30s, 30s+30).
    if (tid < 32) {
        const int bb = tid >> 3, s = tid & 7;
        float v = 0.f;
        #pragma unroll
        for (int w = 0; w < 4; ++w) {
            const int slot = s - (64 * w) / 30;
            if (slot >= 0 && slot < 3) v += sred[w][bb][slot];
        }
        scores[(b0 + bb) * NB + c0 + s] = v;
    }
}

// 64 blocks x 4 waves; wave handles row/col t of the score matrix.
__global__ __launch_bounds__(256) void loss_partial(
    const float* __restrict__ sc, float* __restrict__ partial)
{
    const int wave = threadIdx.x >> 6, lane = threadIdx.x & 63;
    const int t = blockIdx.x * 4 + wave;
    const float dt = sc[t * (NB + 1)];
    float rowmax = 0.f, colmax = 0.f;
    #pragma unroll
    for (int p = 0; p < 4; ++p) {
        const int k = lane + 64 * p;
        const float r = sc[t * NB + k];
        const float c = sc[k * NB + t];
        if (k != t) {
            rowmax = fmaxf(rowmax, 0.2f + r - dt);
            colmax = fmaxf(colmax, 0.2f + c - dt);
        }
    }
    #pragma unroll
    for (int o = 32; o >= 1; o >>= 1) {
        rowmax = fmaxf(rowmax, __shfl_xor(rowmax, o, 64));
        colmax = fmaxf(colmax, __shfl_xor(colmax, o, 64));
    }
    if (lane == 0) partial[t] = fmaxf(rowmax, 0.f) + fmaxf(colmax, 0.f);
}

__global__ __launch_bounds__(256) void loss_final(
    const float* __restrict__ partial, float* __restrict__ out)
{
    const int t = threadIdx.x;
    float v = partial[t];
    __shared__ float red[4];
    #pragma unroll
    for (int o = 32; o >= 1; o >>= 1) v += __shfl_xor(v, o, 64);
    if ((t & 63) == 0) red[t >> 6] = v;
    __syncthreads();
    if (t == 0) out[0] = red[0] + red[1] + red[2] + red[3];
}

extern "C" void kernel_launch(void* const* d_in, const int* in_sizes, int n_in,
                              void* d_out, int out_size, void* d_ws, size_t ws_size,
                              hipStream_t stream) {
    const float* im_set = (const float*)d_in[0];
    const float* s_seq  = (const float*)d_in[1];
    const int*   im_len = (const int*)d_in[2];
    const int*   s_len  = (const int*)d_in[3];
    float* out = (float*)d_out;

    char* ws = (char*)d_ws;
    const size_t imp_bytes = (size_t)NB * LI * DIM * 2;    // 18.9 MB (dense)
    const size_t sp_bytes  = (size_t)NB * LS * DIM * 2;    // 15.7 MB (dense)
    short* imp    = (short*)ws;
    short* sp     = (short*)(ws + imp_bytes);
    float* scores = (float*)(ws + imp_bytes + sp_bytes);   // 256 KB
    float* partial = (float*)(ws + imp_bytes + sp_bytes + (size_t)NB * NB * 4);

    // 256*36 + 256*30 = 16896 rows, one wave each -> 4224 blocks
    normalize_pack<<<4224, 256, 0, stream>>>(im_set, s_seq, imp, sp);

    dim3 grid(NB / 4, NB / 8);
    gemm_scores<<<grid, 256, 0, stream>>>(imp, sp, im_len, s_len, scores);

    loss_partial<<<64, 256, 0, stream>>>(scores, partial);
    loss_final<<<1, 256, 0, stream>>>(partial, out);
}

// Round 5
// 306.313 us; speedup vs baseline: 2.4510x; 2.4510x over previous
//
#include <hip/hip_runtime.h>
#include <hip/hip_bf16.h>

// AlignmentContrastiveLoss on MI355X.
// Pipeline:
//   K1 normalize_pack: fp32 L2-normalize rows of im_set/s_seq, drop CLS/special
//      tokens, cast to bf16. Both packed DENSE: im' [256][36][1024],
//      s' [256][30][1024].
//   K2 gemm_scores: bf16 MFMA GEMM per block: M=144 (4 images x 36),
//      N=240 (8 sentences x 30), K=1024. 4 waves (256 thr), each wave owns
//      4 N-tiles x all 9 M-tiles. DOUBLE-BUFFERED K-pipeline with BK=32:
//      STAGE(next) issued before compute(cur), one barrier/iter.
//      __launch_bounds__(256, 2): 256-reg cap -- acc(144)+rest fits, NO SPILL
//      (R4 post-mortem: the ",3" 170-reg cap spilled acc to scratch, 1.7 GB
//      of HBM writes).
//      Staging: global_load_lds_dwordx4 DMA into LINEAR 64B rows with XOR
//      chunk-swizzle  phys = logical ^ s(row),  s(row) = ((row>>2)+row)&3
//      (row-pairs r/r+4 alias banks mod 32 at 64B stride; plain row&3 XOR
//      left a 2-way conflict -> R4's 1.3e7 conflict cycles). Applied as
//      inverse-swizzled global source + swizzled ds_read (both-sides rule).
//   K3 loss_partial + loss_final: contrastive loss, 64-block parallel.

typedef __attribute__((ext_vector_type(8))) short bf16x8;
typedef __attribute__((ext_vector_type(4))) float f32x4;

#define NB   256
#define DIM  1024
#define LI   36     // valid image regions (dense pack stride)
#define LS   30     // valid words (dense pack stride)
#define MT   9      // M-tiles per block (144 rows)
#define NT   15     // N-tiles per block (240 rows)
#define BUFB 24576  // bytes per LDS buffer: A 9 KB + B 15 KB
#define BOFF 9216   // B region byte offset within a buffer

static __device__ inline ushort f2bf(float x) {
    union { __hip_bfloat16 h; ushort u; } cvt;
    cvt.h = __float2bfloat16(x);
    return cvt.u;
}

static __device__ __forceinline__ void gload_lds16(const void* g, void* l) {
    __builtin_amdgcn_global_load_lds(
        (const __attribute__((address_space(1))) void*)g,
        (__attribute__((address_space(3))) void*)l, 16, 0, 0);
}

// One wave per output row; every row is a real (valid) row.
__global__ __launch_bounds__(256) void normalize_pack(
    const float* __restrict__ im, const float* __restrict__ sq,
    short* __restrict__ imp, short* __restrict__ sp)
{
    const int gw   = (blockIdx.x * 256 + threadIdx.x) >> 6;
    const int lane = threadIdx.x & 63;
    const int NIM  = NB * LI;   // 9216 dense image rows

    const float* src;
    short* dst;
    if (gw < NIM) {
        int b = gw / LI, i = gw - b * LI;
        dst = imp + (size_t)gw * DIM;
        src = im + ((size_t)b * 37 + i + 1) * DIM;   // drop CLS region 0
    } else {
        int g2 = gw - NIM;
        int b = g2 / LS, j = g2 - b * LS;
        dst = sp + (size_t)g2 * DIM;
        src = sq + ((size_t)b * 33 + j + 1) * DIM;   // rows 1..30 of 33
    }

    const float4* s4 = (const float4*)src;
    float4 v[4];
    float ss = 0.f;
    #pragma unroll
    for (int t = 0; t < 4; ++t) {
        float4 x = s4[lane + 64 * t];
        v[t] = x;
        ss += x.x * x.x + x.y * x.y + x.z * x.z + x.w * x.w;
    }
    #pragma unroll
    for (int o = 32; o >= 1; o >>= 1) ss += __shfl_xor(ss, o, 64);
    float scale = 1.0f / fmaxf(sqrtf(ss), 1e-12f);
    ushort4* d4 = (ushort4*)dst;
    #pragma unroll
    for (int t = 0; t < 4; ++t) {
        float4 x = v[t];
        ushort4 o;
        o.x = f2bf(x.x * scale);
        o.y = f2bf(x.y * scale);
        o.z = f2bf(x.z * scale);
        o.w = f2bf(x.w * scale);
        d4[lane + 64 * t] = o;
    }
}

// Block: 256 threads = 4 waves. blockIdx.x -> 4 images (144 dense rows),
// blockIdx.y -> 8 sentences (240 dense rows). Wave w owns N-tiles 4w..4w+3
// (wave 3: tiles 12..14 only), all 9 M-tiles.
//
// LDS per buffer: A rows 0..143 at byte row*64, B rows 0..239 at BOFF+row*64.
// Rows are 32 bf16 = 64 B = 4 chunks of 16 B, XOR-swizzled:
//   physical_chunk = logical_chunk ^ s(row),  s(row) = ((row>>2) + row) & 3
// One DMA instr stages 16 rows (1 KB): lane i -> row r0+(i>>2), phys chunk
// (i&3); global source logical chunk = (i&3) ^ s_i, s_i = ((i>>4)+(i>>2))&3
// [r0 % 16 == 0 so s(row) folds to s_i]. Read side: tile row bases are
// multiples of 16 -> phys chunk = q ^ (((l15>>2)+l15)&3), per-lane constant.
// Verified: every 8-consecutive-lane b128 group covers all 32 banks once
// (reads and linear DMA writes) -> conflict-free.
__global__ __launch_bounds__(256, 2) void gemm_scores(
    const short* __restrict__ imp, const short* __restrict__ sp,
    const int* __restrict__ im_len, const int* __restrict__ s_len,
    float* __restrict__ scores)
{
    __shared__ __align__(1024) char lds[2 * BUFB];   // 48 KB double buffer
    __shared__ float sred[4][4][3];                  // [wave][img][sent-slot]

    const int tid  = threadIdx.x;
    const int wave = tid >> 6;
    const int lane = tid & 63;
    const int q    = lane >> 4;
    const int l15  = lane & 15;
    const int b0   = blockIdx.x * 4;
    const int c0   = blockIdx.y * 8;

    f32x4 acc[MT][4];
    #pragma unroll
    for (int mt = 0; mt < MT; ++mt)
        #pragma unroll
        for (int t = 0; t < 4; ++t)
            acc[mt][t] = (f32x4){0.f, 0.f, 0.f, 0.f};

    // Staging: 24 chunks of 1 KB per K-slice (A: 0..8, B: 9..23), 6 per wave.
    const int r_in = lane >> 2;                          // row within 16-row chunk
    const int sch  = (lane & 3) ^ (((lane >> 4) + (lane >> 2)) & 3);  // inv-swz chunk
    const char* gsrc[6];
    int ldsoff[6];
    #pragma unroll
    for (int it = 0; it < 6; ++it) {
        const int cid = wave * 6 + it;
        ldsoff[it] = cid * 1024;
        if (cid < 9)
            gsrc[it] = (const char*)imp
                + ((size_t)(b0 * LI) + cid * 16 + r_in) * (DIM * 2) + sch * 16;
        else
            gsrc[it] = (const char*)sp
                + ((size_t)(c0 * LS) + (cid - 9) * 16 + r_in) * (DIM * 2) + sch * 16;
    }

    // Read-side swizzled chunk byte offset (per-lane constant).
    const int cs = (q ^ (((l15 >> 2) + l15) & 3)) * 16;

    // prologue: stage K-slice 0 into buffer 0
    #pragma unroll
    for (int it = 0; it < 6; ++it)
        gload_lds16(gsrc[it], lds + ldsoff[it]);
    __syncthreads();   // vmcnt(0) drain

    auto kstep = [&](int curoff, int nxtoff, int kbn, bool do_stage) {
        if (do_stage) {
            #pragma unroll
            for (int it = 0; it < 6; ++it)
                gload_lds16(gsrc[it] + kbn, lds + nxtoff + ldsoff[it]);
        }
        bf16x8 bfr[4];
        #pragma unroll
        for (int t = 0; t < 4; ++t) {
            const int nt = wave * 4 + t;
            if (nt < NT)   // wave-uniform
                bfr[t] = *(const bf16x8*)(lds + curoff + BOFF + (nt * 16 + l15) * 64 + cs);
        }
        #pragma unroll
        for (int mt = 0; mt < MT; ++mt) {
            bf16x8 af = *(const bf16x8*)(lds + curoff + (mt * 16 + l15) * 64 + cs);
            #pragma unroll
            for (int t = 0; t < 4; ++t)
                if (wave * 4 + t < NT)
                    acc[mt][t] = __builtin_amdgcn_mfma_f32_16x16x32_bf16(
                        af, bfr[t], acc[mt][t], 0, 0, 0);
        }
        __syncthreads();   // drains this iter's stage (in flight all compute)
    };

    // 32 K-slices of 32: compute cur while staging next (one barrier/iter).
    for (int kk = 0; kk < 16; ++kk) {
        kstep(0, BUFB, (2 * kk + 1) * 64, true);
        kstep(BUFB, 0, (2 * kk + 2) * 64, kk < 15);
    }

    // ---- Fused epilogue ----
    // C/D layout: lane holds col = l15, row = q*4 + r.
    // Packed A row g = mt*16 + q*4 + r; image = (4*mt+q)/9, region = g - 36*image.
    // Packed B col = nt*16 + l15; sentence sidx = col/30, word j = col - 30*sidx.
    int il[4];
    #pragma unroll
    for (int bb = 0; bb < 4; ++bb) il[bb] = im_len[b0 + bb] - 1;   // in [9, 36]

    // Wave w covers cols [64w, 64w+64) -> up to 3 sentences, base (64w)/30.
    const int sbase = (64 * wave) / 30;
    float part[4][3] = {{0.f,0.f,0.f},{0.f,0.f,0.f},{0.f,0.f,0.f},{0.f,0.f,0.f}};

    #pragma unroll
    for (int t = 0; t < 4; ++t) {
        const int nt = wave * 4 + t;
        if (nt >= NT) continue;                     // wave-uniform
        const int col  = nt * 16 + l15;             // 0..239
        const int sidx = col / 30;                  // per-lane sentence
        const int j    = col - 30 * sidx;           // word index
        const int sl   = s_len[c0 + sidx] - 3;      // valid words, in [5, 30]
        const bool jv  = (j < sl);
        const int s_begin = (nt * 16) / 30;         // wave-uniform
        const int s_end   = (nt * 16 + 15) / 30;

        #pragma unroll
        for (int bb = 0; bb < 4; ++bb) {
            const int ilb = il[bb];
            float m = -3.4e38f;
            #pragma unroll
            for (int mt = 0; mt < MT; ++mt) {
                const int im_lo = (4 * mt) / 9;          // compile-time
                const int im_hi = (4 * mt + 3) / 9;      // compile-time
                const int thr   = 9 * im_hi - 4 * mt;    // q >= thr -> im_hi
                #pragma unroll
                for (int r = 0; r < 4; ++r) {
                    const float v = acc[mt][t][r];
                    const int base = mt * 16 + q * 4 + r;
                    if (im_lo == im_hi) {
                        if (im_lo == bb) {
                            const int i = base - 36 * bb;
                            if (i < ilb) m = fmaxf(m, v);
                        }
                    } else {
                        const bool hi = (q >= thr);
                        if (!hi && im_lo == bb) {
                            const int i = base - 36 * bb;
                            if (i < ilb) m = fmaxf(m, v);
                        } else if (hi && im_hi == bb) {
                            const int i = base - 36 * bb;
                            if (i < ilb) m = fmaxf(m, v);
                        }
                    }
                }
            }
            // combine the 4 row-quads -> full max over image bb's regions
            m = fmaxf(m, __shfl_xor(m, 16, 64));
            m = fmaxf(m, __shfl_xor(m, 32, 64));
            // masked (zeroed) rows participate in the max only when il < 36
            if (ilb < LI) m = fmaxf(m, 0.f);
            const float c = (q == 0 && jv) ? m : 0.f;   // count each col once
            #pragma unroll
            for (int slot = 0; slot < 3; ++slot) {
                const int s = sbase + slot;
                if (s >= s_begin && s <= s_end) {        // wave-uniform
                    float v = (sidx == s) ? c : 0.f;
                    #pragma unroll
                    for (int off = 32; off >= 1; off >>= 1) v += __shfl_xor(v, off, 64);
                    part[bb][slot] += v;
                }
            }
        }
    }

    if (lane == 0) {
        #pragma unroll
        for (int bb = 0; bb < 4; ++bb)
            #pragma unroll
            for (int slot = 0; slot < 3; ++slot)
                sred[wave][bb][slot] = part[bb][slot];
    }
    __syncthreads();
    // 32 score cells: tid -> (bb = tid>>3, s = tid&7); sentence s gathers from
    // the waves whose 64-col window overlaps cols [30s, 30s+30).
    if (tid < 32) {
        const int bb = tid >> 3, s = tid & 7;
        float v = 0.f;
        #pragma unroll
        for (int w = 0; w < 4; ++w) {
            const int slot = s - (64 * w) / 30;
            if (slot >= 0 && slot < 3) v += sred[w][bb][slot];
        }
        scores[(b0 + bb) * NB + c0 + s] = v;
    }
}

// 64 blocks x 4 waves; wave handles row/col t of the score matrix.
__global__ __launch_bounds__(256) void loss_partial(
    const float* __restrict__ sc, float* __restrict__ partial)
{
    const int wave = threadIdx.x >> 6, lane = threadIdx.x & 63;
    const int t = blockIdx.x * 4 + wave;
    const float dt = sc[t * (NB + 1)];
    float rowmax = 0.f, colmax = 0.f;
    #pragma unroll
    for (int p = 0; p < 4; ++p) {
        const int k = lane + 64 * p;
        const float r = sc[t * NB + k];
        const float c = sc[k * NB + t];
        if (k != t) {
            rowmax = fmaxf(rowmax, 0.2f + r - dt);
            colmax = fmaxf(colmax, 0.2f + c - dt);
        }
    }
    #pragma unroll
    for (int o = 32; o >= 1; o >>= 1) {
        rowmax = fmaxf(rowmax, __shfl_xor(rowmax, o, 64));
        colmax = fmaxf(colmax, __shfl_xor(colmax, o, 64));
    }
    if (lane == 0) partial[t] = fmaxf(rowmax, 0.f) + fmaxf(colmax, 0.f);
}

__global__ __launch_bounds__(256) void loss_final(
    const float* __restrict__ partial, float* __restrict__ out)
{
    const int t = threadIdx.x;
    float v = partial[t];
    __shared__ float red[4];
    #pragma unroll
    for (int o = 32; o >= 1; o >>= 1) v += __shfl_xor(v, o, 64);
    if ((t & 63) == 0) red[t >> 6] = v;
    __syncthreads();
    if (t == 0) out[0] = red[0] + red[1] + red[2] + red[3];
}

extern "C" void kernel_launch(void* const* d_in, const int* in_sizes, int n_in,
                              void* d_out, int out_size, void* d_ws, size_t ws_size,
                              hipStream_t stream) {
    const float* im_set = (const float*)d_in[0];
    const float* s_seq  = (const float*)d_in[1];
    const int*   im_len = (const int*)d_in[2];
    const int*   s_len  = (const int*)d_in[3];
    float* out = (float*)d_out;

    char* ws = (char*)d_ws;
    const size_t imp_bytes = (size_t)NB * LI * DIM * 2;    // 18.9 MB (dense)
    const size_t sp_bytes  = (size_t)NB * LS * DIM * 2;    // 15.7 MB (dense)
    short* imp    = (short*)ws;
    short* sp     = (short*)(ws + imp_bytes);
    float* scores = (float*)(ws + imp_bytes + sp_bytes);   // 256 KB
    float* partial = (float*)(ws + imp_bytes + sp_bytes + (size_t)NB * NB * 4);

    // 256*36 + 256*30 = 16896 rows, one wave each -> 4224 blocks
    normalize_pack<<<4224, 256, 0, stream>>>(im_set, s_seq, imp, sp);

    dim3 grid(NB / 4, NB / 8);
    gemm_scores<<<grid, 256, 0, stream>>>(imp, sp, im_len, s_len, scores);

    loss_partial<<<64, 256, 0, stream>>>(scores, partial);
    loss_final<<<1, 256, 0, stream>>>(partial, out);
}